// Round 2
// baseline (256.696 us; speedup 1.0000x reference)
//
#include <hip/hip_runtime.h>
#include <hip/hip_bf16.h>
#include <hip/hip_fp16.h>

// Problem constants
#define B_   2
#define T_   2048
#define DM   2048
#define NH   16
#define DH   128
#define M_   (B_*T_)          // 4096 rows
#define SCALE_ 0.08838834764831845f   // 1/sqrt(128)

typedef _Float16 f16;
typedef f16  half8 __attribute__((ext_vector_type(8)));
typedef f16  half4 __attribute__((ext_vector_type(4)));
typedef float f32x4 __attribute__((ext_vector_type(4)));

#define GL16(gp, lp) __builtin_amdgcn_global_load_lds( \
    (const __attribute__((address_space(1))) void*)(gp), \
    (__attribute__((address_space(3))) void*)(lp), 16, 0, 0)

#define MFMA16(a, b, c) __builtin_amdgcn_mfma_f32_16x16x32_f16((a), (b), (c), 0, 0, 0)

// ---------------- fused fp32 -> fp16 convert (one launch for all 5) ----------------
struct CvtArgs { const float* s[5]; f16* d[5]; };

__global__ __launch_bounds__(256) void convert_all(CvtArgs a) {
    size_t i4 = (size_t)blockIdx.x * 256 + threadIdx.x;
    int r; size_t off;
    if (i4 < 2097152) { r = 0; off = i4; }
    else { size_t k = i4 - 2097152; r = 1 + (int)(k >> 20); off = k & 1048575; }
    float4 v = *((const float4*)a.s[r] + off);
    half4 h;
    h[0] = (f16)v.x; h[1] = (f16)v.y; h[2] = (f16)v.z; h[3] = (f16)v.w;
    *((half4*)a.d[r] + off) = h;
}

// ============ fused QKV GEMM: 256x128 tile, BK=32, 1 barrier/K-tile ============
// Design point (round 2): 2 blocks/CU (LDS 48KB, regs ~115 <= 128) so barrier
// drains are hidden by the co-resident block. One precise vmcnt(0)+barrier per
// K-tile: prefetch for tile t+1 is issued only AFTER the top barrier of tile t,
// so outstanding-at-wait == exactly tile t's 3 loads (no over-drain).
// Wave tile 64x64: 8 ds_read_b128 vs 16 MFMA per K32-tile (ratio 1.49).
// Staging: 64B rows, 4 segs of 16B, seg-swizzle seg^=(row&3) (involution on
// both source and read side, rule #21). Grid 16x48 = 768 = 3 blocks/CU exact.
#define NTQ 64    // K tiles of 32

__global__ __launch_bounds__(512, 4)
void qkv3(const f16* __restrict__ A, const f16* __restrict__ Bw,
          f16* __restrict__ dst)
{
    __shared__ __align__(16) char smem[49152];   // 2 x (16KB A + 8KB B)

    const int tid  = threadIdx.x;
    const int lane = tid & 63;
    const int w    = tid >> 6;
    const int wr   = w >> 1, wc = w & 1;          // 4x2 wave grid

    const int id = (blockIdx.x & 7) * 96 + (blockIdx.x >> 3);
    const int bm = id & 15, bn = id >> 4;
    const int m0 = bm * 256, n0 = bn * 128;

    // staging: thread covers global row (tid>>2), seg (tid&3); source seg is
    // pre-swizzled so linear GL16 dest realizes phys_seg = log_seg ^ (row&3)
    const int scol8 = (((tid & 3) ^ ((tid >> 2) & 3)) << 3);   // elems
    // read side: row = ... + (lane&15) (row&3 == lane&3), logical seg g=lane>>4
    const int rca = (lane & 15) * 64 + ((((lane >> 4) ^ lane) & 3) << 4);

    f32x4 acc[4][4] = {};

#define QA(bufb, s, kt) GL16( \
    A + (size_t)(m0 + (s)*128 + (tid>>2)) * 2048 + (kt)*32 + scol8, \
    smem + (bufb)*24576 + (s)*8192 + w*1024)
#define QB(bufb, kt) GL16( \
    Bw + (size_t)(n0 + (tid>>2)) * 2048 + (kt)*32 + scol8, \
    smem + (bufb)*24576 + 16384 + w*1024)

    QA(0, 0, 0); QA(0, 1, 0); QB(0, 0);

    for (int t = 0; t < NTQ; ++t) {
        const int c = t & 1;
        const char* buf = smem + c * 24576;

        asm volatile("s_waitcnt vmcnt(0)" ::: "memory");  // exactly tile t's loads
        __builtin_amdgcn_s_barrier();
        __builtin_amdgcn_sched_barrier(0);

        if (t + 1 < NTQ) {            // prefetch t+1 into buf c^1 (readers done)
            QA(c ^ 1, 0, t + 1); QA(c ^ 1, 1, t + 1); QB(c ^ 1, t + 1);
        }

        half8 af[4], bf[4];
        #pragma unroll
        for (int m = 0; m < 4; ++m)
            af[m] = *(const half8*)(buf + wr * 4096 + m * 1024 + rca);
        #pragma unroll
        for (int n = 0; n < 4; ++n)
            bf[n] = *(const half8*)(buf + 16384 + wc * 4096 + n * 1024 + rca);

        __builtin_amdgcn_s_setprio(1);
        #pragma unroll
        for (int m = 0; m < 4; ++m)
            #pragma unroll
            for (int n = 0; n < 4; ++n)
                acc[m][n] = MFMA16(af[m], bf[n], acc[m][n]);
        __builtin_amdgcn_s_setprio(0);
    }
#undef QA
#undef QB

    #pragma unroll
    for (int m = 0; m < 4; ++m)
        #pragma unroll
        for (int n = 0; n < 4; ++n)
            #pragma unroll
            for (int j = 0; j < 4; ++j) {
                int row  = m0 + wr * 64 + m * 16 + (lane >> 4) * 4 + j;
                int gcol = n0 + wc * 64 + n * 16 + (lane & 15);
                int sec = gcol >> 11, cic = gcol & 2047;
                int b = row >> 11, tt = row & (T_ - 1);
                int h = cic >> 7, d = cic & 127;
                float cs = (sec == 0) ? SCALE_ : 1.0f;
                dst[(size_t)sec * ((size_t)M_ * 2048) +
                    ((size_t)(b * NH + h) * T_ + tt) * DH + d] = (f16)(acc[m][n][j] * cs);
            }
}

// ============ W_o GEMM: 128x128 tile, 2-phase counted-vmcnt, f32 out ============
// (unchanged — ledger-verified)
#define NT_K 32

__global__ __launch_bounds__(512, 4)
void wo2(const f16* __restrict__ A, const f16* __restrict__ Bw,
         float* __restrict__ Cf)
{
    __shared__ __align__(16) char smem[65536];

    const int tid  = threadIdx.x;
    const int lane = tid & 63;
    const int w    = tid >> 6;
    const int wr   = w >> 2, wc = w & 3;

    const int id = (blockIdx.x & 7) * 64 + (blockIdx.x >> 3);
    const int bm = id & 31, bn = id >> 5;
    const int m0 = bm * 128, n0 = bn * 128;

    const int scol8 = (((tid & 7) ^ ((tid >> 3) & 7)) << 3);
    const int rc0 = (((lane >> 4) * 16)      ) ^ ((lane & 7) << 4);
    const int rc1 = (64 + (lane >> 4) * 16   ) ^ ((lane & 7) << 4);

    f32x4 acc[4][2] = {};

#define WSTAGE_A(bufb, s, kt) GL16( \
    A + (size_t)(m0 + (tid>>8)*64 + (s)*32 + ((tid>>3)&31)) * 2048 + (kt)*64 + scol8, \
    smem + (bufb)*32768 + (s)*8192 + w*1024)
#define WSTAGE_B(bufb, u, kt) GL16( \
    Bw + (size_t)(n0 + (tid>>7)*32 + (u)*16 + ((tid>>3)&15)) * 2048 + (kt)*64 + scol8, \
    smem + (bufb)*32768 + 16384 + (u)*8192 + w*1024)

    WSTAGE_A(0, 0, 0); WSTAGE_A(0, 1, 0);
    WSTAGE_B(0, 0, 0); WSTAGE_B(0, 1, 0);

    const int abase = wr * 4096 + (lane & 15) * 128;
    const int bbase = 16384 + (wc * 16 + (lane & 15)) * 128;

    for (int t = 0; t < NT_K; ++t) {
        const int c  = t & 1;
        const char* buf = smem + c * 32768;
        const int kt = (t + 1 < NT_K) ? t + 1 : t;

        half8 af[4][2], bfr[2];
        // phase 0: A0,A1,B0 resident
        asm volatile("s_waitcnt vmcnt(1)" ::: "memory");
        __builtin_amdgcn_s_barrier();
        __builtin_amdgcn_sched_barrier(0);
        #pragma unroll
        for (int m = 0; m < 4; ++m) {
            const char* p = buf + (m >> 1) * 8192 + abase + (m & 1) * 2048;
            af[m][0] = *(const half8*)(p + rc0);
            af[m][1] = *(const half8*)(p + rc1);
        }
        { const char* p = buf + bbase;
          bfr[0] = *(const half8*)(p + rc0); bfr[1] = *(const half8*)(p + rc1); }
        WSTAGE_A(c ^ 1, 0, kt); WSTAGE_A(c ^ 1, 1, kt);
        __builtin_amdgcn_s_setprio(1);
        #pragma unroll
        for (int m = 0; m < 4; ++m) {
            acc[m][0] = MFMA16(af[m][0], bfr[0], acc[m][0]);
            acc[m][0] = MFMA16(af[m][1], bfr[1], acc[m][0]);
        }
        __builtin_amdgcn_s_setprio(0);

        // phase 1: B1 resident
        asm volatile("s_waitcnt vmcnt(2)" ::: "memory");
        __builtin_amdgcn_s_barrier();
        __builtin_amdgcn_sched_barrier(0);
        { const char* p = buf + bbase + 8192;
          bfr[0] = *(const half8*)(p + rc0); bfr[1] = *(const half8*)(p + rc1); }
        WSTAGE_B(c ^ 1, 0, kt); WSTAGE_B(c ^ 1, 1, kt);
        __builtin_amdgcn_s_setprio(1);
        #pragma unroll
        for (int m = 0; m < 4; ++m) {
            acc[m][1] = MFMA16(af[m][0], bfr[0], acc[m][1]);
            acc[m][1] = MFMA16(af[m][1], bfr[1], acc[m][1]);
        }
        __builtin_amdgcn_s_setprio(0);
        __builtin_amdgcn_s_barrier();
    }
#undef WSTAGE_A
#undef WSTAGE_B

    asm volatile("s_waitcnt vmcnt(0)" ::: "memory");

    #pragma unroll
    for (int m = 0; m < 4; ++m)
        #pragma unroll
        for (int u = 0; u < 2; ++u)
            #pragma unroll
            for (int j = 0; j < 4; ++j) {
                int row = m0 + wr * 64 + m * 16 + (lane >> 4) * 4 + j;
                int col = n0 + wc * 32 + u * 16 + (lane & 15);
                Cf[(size_t)row * 2048 + col] = acc[m][u][j];
            }
}

// ---------------- V transpose: [B,H,T,DH] -> [B,H,DH,T] ----------------
__global__ __launch_bounds__(256)
void vtrans(const f16* __restrict__ Vin, f16* __restrict__ Vout)
{
    __shared__ f16 ld[64][72];
    const int tid = threadIdx.x;
    const int dd = blockIdx.x;          // 0..1  (d-half)
    const int tt = blockIdx.y;          // 0..31 (t-tile)
    const int bh = blockIdx.z;          // 0..31

    const int r  = tid >> 2;            // 0..63
    const int s2 = (tid & 3) * 2;       // seg pair: 0,2,4,6

    const f16* src = Vin + ((size_t)bh * T_ + tt * 64 + r) * DH + dd * 64;
    half8 v0 = *(const half8*)(src + s2 * 8);
    half8 v1 = *(const half8*)(src + s2 * 8 + 8);
    #pragma unroll
    for (int e = 0; e < 8; ++e) ld[s2 * 8 + e][r]     = v0[e];
    #pragma unroll
    for (int e = 0; e < 8; ++e) ld[s2 * 8 + 8 + e][r] = v1[e];
    __syncthreads();

    f16* dst = Vout + ((size_t)bh * DH + dd * 64 + r) * T_ + tt * 64;
    *(half8*)(dst + s2 * 8)     = *(const half8*)&ld[r][s2 * 8];
    *(half8*)(dst + s2 * 8 + 8) = *(const half8*)&ld[r][s2 * 8 + 8];
}

// ---------------- causal flash attention: swapped-QK^T + pre-transposed V ----------------
#define QB 64
#define KB 64
#define PP 72
#define NQT (T_/QB)   // 32

__global__ __launch_bounds__(256, 4)
void attn_fwd(const f16* __restrict__ Q, const f16* __restrict__ K,
              const f16* __restrict__ Vt, f16* __restrict__ O)
{
    __shared__ __align__(16) char Ks[2][16384];   // 64 k-rows x 256B (swz)
    __shared__ __align__(16) char Vs[2][16384];   // 128 d-rows x 128B (swz)
    __shared__ __align__(16) f16 Ps[4][16][PP];

    const int tid  = threadIdx.x;
    const int lane = tid & 63;
    const int w    = tid >> 6;
    const int g    = lane >> 4;

    const int bid  = blockIdx.x;
    const int swz  = (bid & 7) * 64 + (bid >> 3);
    const int bh   = swz >> 4;
    const int pair = swz & 15;
    const size_t base = (size_t)bh * T_ * DH;     // == bh*DH*T_ (V^T base)
    const int b = bh >> 4, h = bh & 15;

    const int krow0 = w * 4 + g;
    const int kswz  = ((lane & 15) ^ (krow0 & 7)) << 3;          // elems
    const int vrow0 = w * 8 + (lane >> 3);
    const int vswz  = (((lane & 7) ^ ((lane >> 3) & 7)) << 3);   // elems

#define STAGE_K(c_, kv) do { \
    _Pragma("unroll") for (int i_ = 0; i_ < 4; ++i_) { \
        const f16* g_ = K + base + (size_t)((kv) + i_*16 + krow0) * DH + kswz; \
        GL16(g_, &Ks[c_][i_*4096 + w*1024]); } } while (0)
#define STAGE_V(c_, kv) do { \
    _Pragma("unroll") for (int i_ = 0; i_ < 4; ++i_) { \
        const f16* g_ = Vt + base + (size_t)(i_*32 + vrow0) * T_ + (kv) + vswz; \
        GL16(g_, &Vs[c_][i_*4096 + w*1024]); } } while (0)

    #pragma unroll
    for (int hf = 0; hf < 2; ++hf) {
        const int qt = (hf == 0) ? pair : (NQT - 1 - pair);
        const int q0 = qt * QB;
        const int ntiles = qt + 1;
        const int qg = q0 + w * 16 + (lane & 15);   // this lane's q-row

        half8 qf[4];
        #pragma unroll
        for (int kk = 0; kk < 4; ++kk)
            qf[kk] = *reinterpret_cast<const half8*>(
                &Q[base + (size_t)qg * DH + kk * 32 + g * 8]);

        float mrun = -1e30f, lrun = 0.f;
        f32x4 o[8] = {};   // o[n][j] = O^T[d = n*16+g*4+j][q = lane&15]

        __syncthreads();          // prev half's readers done before restaging
        STAGE_K(0, 0);
        STAGE_V(0, 0);

        for (int it = 0; it < ntiles; ++it) {
            const int c = it & 1;
            __syncthreads();      // vmcnt(0) drain: tile-it K/V resident
            if (it + 1 < ntiles) {
                STAGE_K(c ^ 1, (it + 1) * KB);
                STAGE_V(c ^ 1, (it + 1) * KB);
            }

            // S^T = K·Q^T (swapped operands; lane owns q-row = lane&15)
            const char* kb = &Ks[c][0];
            f32x4 sacc[4] = {};
            __builtin_amdgcn_s_setprio(1);
            #pragma unroll
            for (int n = 0; n < 4; ++n)
                #pragma unroll
                for (int kk = 0; kk < 4; ++kk) {
                    half8 kfv = *(const half8*)(kb + (n*16 + (lane & 15)) * 256 +
                        ((kk*32 + g * 8) * 2 ^ ((lane & 7) << 4)));
                    sacc[n] = MFMA16(kfv, qf[kk], sacc[n]);
                }
            __builtin_amdgcn_s_setprio(0);

            // causal mask (diagonal tile)
            if (it == ntiles - 1) {
                #pragma unroll
                for (int n = 0; n < 4; ++n)
                    #pragma unroll
                    for (int j = 0; j < 4; ++j) {
                        int kg = it * KB + n*16 + g*4 + j;
                        if (kg > qg) sacc[n][j] = -1e30f;
                    }
            }

            // lane-local online softmax
            float mx = sacc[0][0];
            #pragma unroll
            for (int n = 0; n < 4; ++n)
                #pragma unroll
                for (int j = 0; j < 4; ++j) mx = fmaxf(mx, sacc[n][j]);
            mx = fmaxf(mx, __shfl_xor(mx, 16));
            mx = fmaxf(mx, __shfl_xor(mx, 32));
            float mnew = fmaxf(mrun, mx);
            float sf = __expf(mrun - mnew);
            float rs = 0.f;
            #pragma unroll
            for (int n = 0; n < 4; ++n)
                #pragma unroll
                for (int j = 0; j < 4; ++j) {
                    float p = __expf(sacc[n][j] - mnew);
                    sacc[n][j] = p;
                    rs += p;
                }
            rs += __shfl_xor(rs, 16);
            rs += __shfl_xor(rs, 32);
            lrun = lrun * sf + rs;
            mrun = mnew;
            #pragma unroll
            for (int nn = 0; nn < 8; ++nn) o[nn] *= sf;

            // P[q][k] -> Ps (half4 per n; 2-way bank = free)
            #pragma unroll
            for (int n = 0; n < 4; ++n) {
                half4 hv;
                hv[0] = (f16)sacc[n][0]; hv[1] = (f16)sacc[n][1];
                hv[2] = (f16)sacc[n][2]; hv[3] = (f16)sacc[n][3];
                *reinterpret_cast<half4*>(&Ps[w][lane & 15][n*16 + g*4]) = hv;
            }

            // B-frags of P
            half8 bp[2];
            #pragma unroll
            for (int cc = 0; cc < 2; ++cc)
                bp[cc] = *reinterpret_cast<const half8*>(&Ps[w][lane & 15][cc*32 + g*8]);

            // O^T += V^T·P
            const char* vb = &Vs[c][0];
            __builtin_amdgcn_s_setprio(1);
            #pragma unroll
            for (int n = 0; n < 8; ++n)
                #pragma unroll
                for (int cc = 0; cc < 2; ++cc) {
                    half8 vf = *(const half8*)(vb + (n*16 + (lane & 15)) * 128 +
                        ((cc*64 + g*16) ^ ((lane & 7) << 4)));
                    o[n] = MFMA16(vf, bp[cc], o[n]);
                }
            __builtin_amdgcn_s_setprio(0);
        }

        // epilogue
        float invl = 1.0f / lrun;
        #pragma unroll
        for (int n = 0; n < 8; ++n) {
            half4 hv;
            hv[0] = (f16)(o[n][0] * invl); hv[1] = (f16)(o[n][1] * invl);
            hv[2] = (f16)(o[n][2] * invl); hv[3] = (f16)(o[n][3] * invl);
            *reinterpret_cast<half4*>(
                &O[((size_t)(b * T_ + qg) * NH + h) * DH + n*16 + g*4]) = hv;
        }
    }
#undef STAGE_K
#undef STAGE_V
}

// ---------------- launch ----------------
extern "C" void kernel_launch(void* const* d_in, const int* in_sizes, int n_in,
                              void* d_out, int out_size, void* d_ws, size_t ws_size,
                              hipStream_t stream)
{
    const float* x  = (const float*)d_in[0];
    const float* wq = (const float*)d_in[1];
    const float* wk = (const float*)d_in[2];
    const float* wv = (const float*)d_in[3];
    const float* wo = (const float*)d_in[4];
    float* out = (float*)d_out;

    const size_t nx = (size_t)M_ * DM;   // 8388608
    const size_t nw = (size_t)DM * DM;   // 4194304
    const size_t need = (nx * 5 + nw * 4) * sizeof(f16);  // ~117 MB
    if (ws_size < need) return;

    char* ws = (char*)d_ws;
    f16* xh  = (f16*)ws;  ws += nx * 2;   // after qkv3: dead -> reused as V^T
    f16* wqh = (f16*)ws;  ws += nw * 2;   // wq,wk,wv contiguous -> fused B [6144,2048]
    f16* wkh = (f16*)ws;  ws += nw * 2;
    f16* wvh = (f16*)ws;  ws += nw * 2;
    f16* woh = (f16*)ws;  ws += nw * 2;
    f16* Qh  = (f16*)ws;  ws += nx * 2;   // Q,K,V contiguous -> fused dst
    f16* Kh  = (f16*)ws;  ws += nx * 2;
    f16* Vh  = (f16*)ws;  ws += nx * 2;
    f16* Oh  = (f16*)ws;  ws += nx * 2;

    f16* Vth = xh;   // V^T [B,H,DH,T] aliases xh (x consumed by qkv3 first)

    CvtArgs ca;
    ca.s[0] = x;  ca.d[0] = xh;
    ca.s[1] = wq; ca.d[1] = wqh;
    ca.s[2] = wk; ca.d[2] = wkh;
    ca.s[3] = wv; ca.d[3] = wvh;
    ca.s[4] = wo; ca.d[4] = woh;
    convert_all<<<24576, 256, 0, stream>>>(ca);

    qkv3<<<dim3(768), 512, 0, stream>>>(xh, wqh, Qh);

    vtrans<<<dim3(2, 32, 32), 256, 0, stream>>>(Vh, Vth);

    attn_fwd<<<dim3(512), 256, 0, stream>>>(Qh, Kh, Vth, Oh);

    wo2<<<dim3(512), 512, 0, stream>>>(Oh, woh, out);
}

// Round 3
// 234.438 us; speedup vs baseline: 1.0949x; 1.0949x over previous
//
#include <hip/hip_runtime.h>
#include <hip/hip_bf16.h>
#include <hip/hip_fp16.h>

// Problem constants
#define B_   2
#define T_   2048
#define DM   2048
#define NH   16
#define DH   128
#define M_   (B_*T_)          // 4096 rows
#define SCALE_ 0.08838834764831845f   // 1/sqrt(128)

typedef _Float16 f16;
typedef f16  half8 __attribute__((ext_vector_type(8)));
typedef f16  half4 __attribute__((ext_vector_type(4)));
typedef float f32x4 __attribute__((ext_vector_type(4)));

#define GL16(gp, lp) __builtin_amdgcn_global_load_lds( \
    (const __attribute__((address_space(1))) void*)(gp), \
    (__attribute__((address_space(3))) void*)(lp), 16, 0, 0)

#define MFMA16(a, b, c) __builtin_amdgcn_mfma_f32_16x16x32_f16((a), (b), (c), 0, 0, 0)

// ---------------- fused fp32 -> fp16 convert (one launch for all 5) ----------------
struct CvtArgs { const float* s[5]; f16* d[5]; };

__global__ __launch_bounds__(256) void convert_all(CvtArgs a) {
    size_t i4 = (size_t)blockIdx.x * 256 + threadIdx.x;
    int r; size_t off;
    if (i4 < 2097152) { r = 0; off = i4; }
    else { size_t k = i4 - 2097152; r = 1 + (int)(k >> 20); off = k & 1048575; }
    float4 v = *((const float4*)a.s[r] + off);
    half4 h;
    h[0] = (f16)v.x; h[1] = (f16)v.y; h[2] = (f16)v.z; h[3] = (f16)v.w;
    *((half4*)a.d[r] + off) = h;
}

// ============ fused QKV GEMM: 256x192 tile, one-phase-ahead pipelined ============
// R1 geometry (ledger-verified, 0 bank conflicts) + software-pipelined LDS reads:
// every MFMA cluster consumes frags whose ds_reads were issued one phase earlier,
// so the LDS-read pipe (1920 cyc/tile) overlaps the MFMA pipe (1862 cyc/tile)
// instead of serializing with it (R1 measured the sum, 3660 cyc/tile).
// Gates shifted one phase early; per-tile ledger (stage A0',A1'@ph0; A2',A3'@ph1;
// B0'@ph2; B1'@ph3; B2'@ph4; entering-ph0 outstanding {B1,B2}):
//   ph1: vmcnt(3) [needs B1]   ph3: vmcnt(5) [needs B2]   ph4: vmcnt(1) [A0-3',B0']
// Exit outstanding {B1',B2'} == entry. A-frags double-buffered in regs (af0/af1,
// x2-unrolled loop for static indexing).
#define NT_K 32

__global__ __launch_bounds__(512, 2)
void qkv3(const f16* __restrict__ A, const f16* __restrict__ Bw,
          f16* __restrict__ dst)
{
    __shared__ __align__(16) char smem[114688];   // 2 x (32KB A + 24KB B)

    const int tid  = threadIdx.x;
    const int lane = tid & 63;
    const int w    = tid >> 6;
    const int wr   = w >> 1, wc = w & 1;          // 4x2 wave grid

    const int id = (blockIdx.x & 7) * 64 + (blockIdx.x >> 3);
    const int bm = id & 15, bn = id >> 4;
    const int m0 = bm * 256, n0 = bn * 192;

    const int scol8 = (((tid & 7) ^ ((tid >> 3) & 7)) << 3);
    const int rc0 = (((lane >> 4) * 16)      ) ^ ((lane & 7) << 4);
    const int rc1 = (64 + (lane >> 4) * 16   ) ^ ((lane & 7) << 4);

    f32x4 acc[4][6] = {};

#define QSTAGE_A(bufb, ch, s, kt) GL16( \
    A + (size_t)(m0 + (ch)*128 + (tid>>8)*64 + (s)*32 + ((tid>>3)&31)) * 2048 + (kt)*64 + scol8, \
    smem + (bufb)*57344 + (ch)*16384 + (s)*8192 + w*1024)
#define QSTAGE_B(bufb, u, kt) GL16( \
    Bw + (size_t)(n0 + (tid>>7)*48 + (u)*16 + ((tid>>3)&15)) * 2048 + (kt)*64 + scol8, \
    smem + (bufb)*57344 + 32768 + (u)*8192 + w*1024)

    // A rows: af[m] region offset = (m>>1)*8192 + (m&1)*2048 from abase
    const int abase = (wr >> 1) * 16384 + (wr & 1) * 4096 + (lane & 15) * 128;
    // B cols: f regions: f0:+0 f3:+2048 f1:+8192 f4:+10240 f2:+16384 f5:+18432
    const int bbase = 32768 + wc * 4096 + (lane & 15) * 128;

    half8 af0[4][2], af1[4][2], bnx[2];

    // prologue: stage tile 0, gate A0-3+B0 (allow B1,B2 in flight), preload frags
    QSTAGE_A(0, 0, 0, 0); QSTAGE_A(0, 0, 1, 0);
    QSTAGE_A(0, 1, 0, 0); QSTAGE_A(0, 1, 1, 0);
    QSTAGE_B(0, 0, 0);    QSTAGE_B(0, 1, 0);    QSTAGE_B(0, 2, 0);
    {
        asm volatile("s_waitcnt vmcnt(2)" ::: "memory");
        __builtin_amdgcn_s_barrier();
        __builtin_amdgcn_sched_barrier(0);
        const char* buf0 = smem;
        #pragma unroll
        for (int m = 0; m < 4; ++m) {
            const char* p = buf0 + (m >> 1) * 8192 + abase + (m & 1) * 2048;
            af0[m][0] = *(const half8*)(p + rc0);
            af0[m][1] = *(const half8*)(p + rc1);
        }
        bnx[0] = *(const half8*)(buf0 + bbase + rc0);
        bnx[1] = *(const half8*)(buf0 + bbase + rc1);
    }

#define GATE(n_) do { \
    asm volatile("s_waitcnt vmcnt(" #n_ ")" ::: "memory"); \
    __builtin_amdgcn_s_barrier(); \
    __builtin_amdgcn_sched_barrier(0); \
} while (0)

#define MFC(AF, BB, f_) do { \
    __builtin_amdgcn_s_setprio(1); \
    _Pragma("unroll") \
    for (int m_ = 0; m_ < 4; ++m_) { \
        acc[m_][f_] = MFMA16(AF[m_][0], (BB)[0], acc[m_][f_]); \
        acc[m_][f_] = MFMA16(AF[m_][1], (BB)[1], acc[m_][f_]); \
    } \
    __builtin_amdgcn_s_setprio(0); \
} while (0)

#define RDB(dstv, off) do { \
    const char* p_ = buf + bbase + (off); \
    dstv[0] = *(const half8*)(p_ + rc0); \
    dstv[1] = *(const half8*)(p_ + rc1); \
} while (0)

#define BODY(t_, c_, AFC, AFN) do { \
    const char* buf  = smem + (c_) * 57344; \
    const char* nbuf = smem + ((c_) ^ 1) * 57344; \
    const int  kt    = ((t_) + 1 < NT_K) ? (t_) + 1 : (t_); \
    half8 b3[2], b1[2], b4[2], b2[2], b5[2]; \
    /* ph0: reads b(f3); stage A0',A1'; MFMA f0 */ \
    RDB(b3, 2048); \
    QSTAGE_A((c_) ^ 1, 0, 0, kt); QSTAGE_A((c_) ^ 1, 0, 1, kt); \
    MFC(AFC, bnx, 0); \
    /* ph1: gate B1; reads b(f1); stage A2',A3'; MFMA f3 */ \
    GATE(3); \
    RDB(b1, 8192); \
    QSTAGE_A((c_) ^ 1, 1, 0, kt); QSTAGE_A((c_) ^ 1, 1, 1, kt); \
    MFC(AFC, b3, 3); \
    /* ph2: reads b(f4); stage B0'; MFMA f1 */ \
    RDB(b4, 8192 + 2048); \
    QSTAGE_B((c_) ^ 1, 0, kt); \
    MFC(AFC, b1, 1); \
    /* ph3: gate B2; reads b(f2); stage B1'; MFMA f4 */ \
    GATE(5); \
    RDB(b2, 16384); \
    QSTAGE_B((c_) ^ 1, 1, kt); \
    MFC(AFC, b4, 4); \
    /* ph4: gate A0-3'+B0'; reads b(f5)+af'[0..1]; stage B2'; MFMA f2 */ \
    GATE(1); \
    RDB(b5, 16384 + 2048); \
    { const char* p_ = nbuf + abase; \
      AFN[0][0] = *(const half8*)(p_ + rc0); \
      AFN[0][1] = *(const half8*)(p_ + rc1); \
      AFN[1][0] = *(const half8*)(p_ + 2048 + rc0); \
      AFN[1][1] = *(const half8*)(p_ + 2048 + rc1); } \
    QSTAGE_B((c_) ^ 1, 2, kt); \
    MFC(AFC, b2, 2); \
    /* ph5: reads af'[2..3] + b'(f0); MFMA f5 */ \
    { const char* p_ = nbuf + 8192 + abase; \
      AFN[2][0] = *(const half8*)(p_ + rc0); \
      AFN[2][1] = *(const half8*)(p_ + rc1); \
      AFN[3][0] = *(const half8*)(p_ + 2048 + rc0); \
      AFN[3][1] = *(const half8*)(p_ + 2048 + rc1); } \
    { const char* p_ = nbuf + bbase; \
      bnx[0] = *(const half8*)(p_ + rc0); \
      bnx[1] = *(const half8*)(p_ + rc1); } \
    MFC(AFC, b5, 5); \
} while (0)

    for (int t = 0; t < NT_K; t += 2) {
        BODY(t,     0, af0, af1);
        BODY(t + 1, 1, af1, af0);
    }
#undef BODY
#undef RDB
#undef MFC
#undef GATE
#undef QSTAGE_A
#undef QSTAGE_B

    asm volatile("s_waitcnt vmcnt(0)" ::: "memory");

    #pragma unroll
    for (int m = 0; m < 4; ++m)
        #pragma unroll
        for (int f = 0; f < 6; ++f)
            #pragma unroll
            for (int j = 0; j < 4; ++j) {
                int row  = m0 + wr * 64 + m * 16 + (lane >> 4) * 4 + j;
                int gcol = n0 + wc * 96 + f * 16 + (lane & 15);
                int sec = gcol >> 11, cic = gcol & 2047;
                int b = row >> 11, tt = row & (T_ - 1);
                int h = cic >> 7, d = cic & 127;
                float cs = (sec == 0) ? SCALE_ : 1.0f;
                dst[(size_t)sec * ((size_t)M_ * 2048) +
                    ((size_t)(b * NH + h) * T_ + tt) * DH + d] = (f16)(acc[m][f][j] * cs);
            }
}

// ============ W_o GEMM: 128x128 tile, 2-phase counted-vmcnt, f32 out ============
// (unchanged — ledger-verified)
__global__ __launch_bounds__(512, 4)
void wo2(const f16* __restrict__ A, const f16* __restrict__ Bw,
         float* __restrict__ Cf)
{
    __shared__ __align__(16) char smem[65536];

    const int tid  = threadIdx.x;
    const int lane = tid & 63;
    const int w    = tid >> 6;
    const int wr   = w >> 2, wc = w & 3;

    const int id = (blockIdx.x & 7) * 64 + (blockIdx.x >> 3);
    const int bm = id & 31, bn = id >> 5;
    const int m0 = bm * 128, n0 = bn * 128;

    const int scol8 = (((tid & 7) ^ ((tid >> 3) & 7)) << 3);
    const int rc0 = (((lane >> 4) * 16)      ) ^ ((lane & 7) << 4);
    const int rc1 = (64 + (lane >> 4) * 16   ) ^ ((lane & 7) << 4);

    f32x4 acc[4][2] = {};

#define WSTAGE_A(bufb, s, kt) GL16( \
    A + (size_t)(m0 + (tid>>8)*64 + (s)*32 + ((tid>>3)&31)) * 2048 + (kt)*64 + scol8, \
    smem + (bufb)*32768 + (s)*8192 + w*1024)
#define WSTAGE_B(bufb, u, kt) GL16( \
    Bw + (size_t)(n0 + (tid>>7)*32 + (u)*16 + ((tid>>3)&15)) * 2048 + (kt)*64 + scol8, \
    smem + (bufb)*32768 + 16384 + (u)*8192 + w*1024)

    WSTAGE_A(0, 0, 0); WSTAGE_A(0, 1, 0);
    WSTAGE_B(0, 0, 0); WSTAGE_B(0, 1, 0);

    const int abase = wr * 4096 + (lane & 15) * 128;
    const int bbase = 16384 + (wc * 16 + (lane & 15)) * 128;

    for (int t = 0; t < NT_K; ++t) {
        const int c  = t & 1;
        const char* buf = smem + c * 32768;
        const int kt = (t + 1 < NT_K) ? t + 1 : t;

        half8 af[4][2], bfr[2];
        // phase 0: A0,A1,B0 resident
        asm volatile("s_waitcnt vmcnt(1)" ::: "memory");
        __builtin_amdgcn_s_barrier();
        __builtin_amdgcn_sched_barrier(0);
        #pragma unroll
        for (int m = 0; m < 4; ++m) {
            const char* p = buf + (m >> 1) * 8192 + abase + (m & 1) * 2048;
            af[m][0] = *(const half8*)(p + rc0);
            af[m][1] = *(const half8*)(p + rc1);
        }
        { const char* p = buf + bbase;
          bfr[0] = *(const half8*)(p + rc0); bfr[1] = *(const half8*)(p + rc1); }
        WSTAGE_A(c ^ 1, 0, kt); WSTAGE_A(c ^ 1, 1, kt);
        __builtin_amdgcn_s_setprio(1);
        #pragma unroll
        for (int m = 0; m < 4; ++m) {
            acc[m][0] = MFMA16(af[m][0], bfr[0], acc[m][0]);
            acc[m][0] = MFMA16(af[m][1], bfr[1], acc[m][0]);
        }
        __builtin_amdgcn_s_setprio(0);

        // phase 1: B1 resident
        asm volatile("s_waitcnt vmcnt(2)" ::: "memory");
        __builtin_amdgcn_s_barrier();
        __builtin_amdgcn_sched_barrier(0);
        { const char* p = buf + bbase + 8192;
          bfr[0] = *(const half8*)(p + rc0); bfr[1] = *(const half8*)(p + rc1); }
        WSTAGE_B(c ^ 1, 0, kt); WSTAGE_B(c ^ 1, 1, kt);
        __builtin_amdgcn_s_setprio(1);
        #pragma unroll
        for (int m = 0; m < 4; ++m) {
            acc[m][1] = MFMA16(af[m][0], bfr[0], acc[m][1]);
            acc[m][1] = MFMA16(af[m][1], bfr[1], acc[m][1]);
        }
        __builtin_amdgcn_s_setprio(0);
        __builtin_amdgcn_s_barrier();
    }
#undef WSTAGE_A
#undef WSTAGE_B

    asm volatile("s_waitcnt vmcnt(0)" ::: "memory");

    #pragma unroll
    for (int m = 0; m < 4; ++m)
        #pragma unroll
        for (int u = 0; u < 2; ++u)
            #pragma unroll
            for (int j = 0; j < 4; ++j) {
                int row = m0 + wr * 64 + m * 16 + (lane >> 4) * 4 + j;
                int col = n0 + wc * 32 + u * 16 + (lane & 15);
                Cf[(size_t)row * 2048 + col] = acc[m][u][j];
            }
}

// ---------------- V transpose: [B,H,T,DH] -> [B,H,DH,T] ----------------
__global__ __launch_bounds__(256)
void vtrans(const f16* __restrict__ Vin, f16* __restrict__ Vout)
{
    __shared__ f16 ld[64][72];
    const int tid = threadIdx.x;
    const int dd = blockIdx.x;          // 0..1  (d-half)
    const int tt = blockIdx.y;          // 0..31 (t-tile)
    const int bh = blockIdx.z;          // 0..31

    const int r  = tid >> 2;            // 0..63
    const int s2 = (tid & 3) * 2;       // seg pair: 0,2,4,6

    const f16* src = Vin + ((size_t)bh * T_ + tt * 64 + r) * DH + dd * 64;
    half8 v0 = *(const half8*)(src + s2 * 8);
    half8 v1 = *(const half8*)(src + s2 * 8 + 8);
    #pragma unroll
    for (int e = 0; e < 8; ++e) ld[s2 * 8 + e][r]     = v0[e];
    #pragma unroll
    for (int e = 0; e < 8; ++e) ld[s2 * 8 + 8 + e][r] = v1[e];
    __syncthreads();

    f16* dst = Vout + ((size_t)bh * DH + dd * 64 + r) * T_ + tt * 64;
    *(half8*)(dst + s2 * 8)     = *(const half8*)&ld[r][s2 * 8];
    *(half8*)(dst + s2 * 8 + 8) = *(const half8*)&ld[r][s2 * 8 + 8];
}

// ---------------- causal flash attention: swapped-QK^T + pre-transposed V ----------------
#define QB 64
#define KB 64
#define PP 72
#define NQT (T_/QB)   // 32

__global__ __launch_bounds__(256, 4)
void attn_fwd(const f16* __restrict__ Q, const f16* __restrict__ K,
              const f16* __restrict__ Vt, f16* __restrict__ O)
{
    __shared__ __align__(16) char Ks[2][16384];   // 64 k-rows x 256B (swz)
    __shared__ __align__(16) char Vs[2][16384];   // 128 d-rows x 128B (swz)
    __shared__ __align__(16) f16 Ps[4][16][PP];

    const int tid  = threadIdx.x;
    const int lane = tid & 63;
    const int w    = tid >> 6;
    const int g    = lane >> 4;

    const int bid  = blockIdx.x;
    const int swz  = (bid & 7) * 64 + (bid >> 3);
    const int bh   = swz >> 4;
    const int pair = swz & 15;
    const size_t base = (size_t)bh * T_ * DH;     // == bh*DH*T_ (V^T base)
    const int b = bh >> 4, h = bh & 15;

    const int krow0 = w * 4 + g;
    const int kswz  = ((lane & 15) ^ (krow0 & 7)) << 3;          // elems
    const int vrow0 = w * 8 + (lane >> 3);
    const int vswz  = (((lane & 7) ^ ((lane >> 3) & 7)) << 3);   // elems

#define STAGE_K(c_, kv) do { \
    _Pragma("unroll") for (int i_ = 0; i_ < 4; ++i_) { \
        const f16* g_ = K + base + (size_t)((kv) + i_*16 + krow0) * DH + kswz; \
        GL16(g_, &Ks[c_][i_*4096 + w*1024]); } } while (0)
#define STAGE_V(c_, kv) do { \
    _Pragma("unroll") for (int i_ = 0; i_ < 4; ++i_) { \
        const f16* g_ = Vt + base + (size_t)(i_*32 + vrow0) * T_ + (kv) + vswz; \
        GL16(g_, &Vs[c_][i_*4096 + w*1024]); } } while (0)

    #pragma unroll
    for (int hf = 0; hf < 2; ++hf) {
        const int qt = (hf == 0) ? pair : (NQT - 1 - pair);
        const int q0 = qt * QB;
        const int ntiles = qt + 1;
        const int qg = q0 + w * 16 + (lane & 15);   // this lane's q-row

        half8 qf[4];
        #pragma unroll
        for (int kk = 0; kk < 4; ++kk)
            qf[kk] = *reinterpret_cast<const half8*>(
                &Q[base + (size_t)qg * DH + kk * 32 + g * 8]);

        float mrun = -1e30f, lrun = 0.f;
        f32x4 o[8] = {};   // o[n][j] = O^T[d = n*16+g*4+j][q = lane&15]

        __syncthreads();          // prev half's readers done before restaging
        STAGE_K(0, 0);
        STAGE_V(0, 0);

        for (int it = 0; it < ntiles; ++it) {
            const int c = it & 1;
            __syncthreads();      // vmcnt(0) drain: tile-it K/V resident
            if (it + 1 < ntiles) {
                STAGE_K(c ^ 1, (it + 1) * KB);
                STAGE_V(c ^ 1, (it + 1) * KB);
            }

            // S^T = K·Q^T (swapped operands; lane owns q-row = lane&15)
            const char* kb = &Ks[c][0];
            f32x4 sacc[4] = {};
            __builtin_amdgcn_s_setprio(1);
            #pragma unroll
            for (int n = 0; n < 4; ++n)
                #pragma unroll
                for (int kk = 0; kk < 4; ++kk) {
                    half8 kfv = *(const half8*)(kb + (n*16 + (lane & 15)) * 256 +
                        ((kk*32 + g * 8) * 2 ^ ((lane & 7) << 4)));
                    sacc[n] = MFMA16(kfv, qf[kk], sacc[n]);
                }
            __builtin_amdgcn_s_setprio(0);

            // causal mask (diagonal tile)
            if (it == ntiles - 1) {
                #pragma unroll
                for (int n = 0; n < 4; ++n)
                    #pragma unroll
                    for (int j = 0; j < 4; ++j) {
                        int kg = it * KB + n*16 + g*4 + j;
                        if (kg > qg) sacc[n][j] = -1e30f;
                    }
            }

            // lane-local online softmax
            float mx = sacc[0][0];
            #pragma unroll
            for (int n = 0; n < 4; ++n)
                #pragma unroll
                for (int j = 0; j < 4; ++j) mx = fmaxf(mx, sacc[n][j]);
            mx = fmaxf(mx, __shfl_xor(mx, 16));
            mx = fmaxf(mx, __shfl_xor(mx, 32));
            float mnew = fmaxf(mrun, mx);
            float sf = __expf(mrun - mnew);
            float rs = 0.f;
            #pragma unroll
            for (int n = 0; n < 4; ++n)
                #pragma unroll
                for (int j = 0; j < 4; ++j) {
                    float p = __expf(sacc[n][j] - mnew);
                    sacc[n][j] = p;
                    rs += p;
                }
            rs += __shfl_xor(rs, 16);
            rs += __shfl_xor(rs, 32);
            lrun = lrun * sf + rs;
            mrun = mnew;
            #pragma unroll
            for (int nn = 0; nn < 8; ++nn) o[nn] *= sf;

            // P[q][k] -> Ps (half4 per n; 2-way bank = free)
            #pragma unroll
            for (int n = 0; n < 4; ++n) {
                half4 hv;
                hv[0] = (f16)sacc[n][0]; hv[1] = (f16)sacc[n][1];
                hv[2] = (f16)sacc[n][2]; hv[3] = (f16)sacc[n][3];
                *reinterpret_cast<half4*>(&Ps[w][lane & 15][n*16 + g*4]) = hv;
            }

            // B-frags of P
            half8 bp[2];
            #pragma unroll
            for (int cc = 0; cc < 2; ++cc)
                bp[cc] = *reinterpret_cast<const half8*>(&Ps[w][lane & 15][cc*32 + g*8]);

            // O^T += V^T·P
            const char* vb = &Vs[c][0];
            __builtin_amdgcn_s_setprio(1);
            #pragma unroll
            for (int n = 0; n < 8; ++n)
                #pragma unroll
                for (int cc = 0; cc < 2; ++cc) {
                    half8 vf = *(const half8*)(vb + (n*16 + (lane & 15)) * 128 +
                        ((cc*64 + g*16) ^ ((lane & 7) << 4)));
                    o[n] = MFMA16(vf, bp[cc], o[n]);
                }
            __builtin_amdgcn_s_setprio(0);
        }

        // epilogue
        float invl = 1.0f / lrun;
        #pragma unroll
        for (int n = 0; n < 8; ++n) {
            half4 hv;
            hv[0] = (f16)(o[n][0] * invl); hv[1] = (f16)(o[n][1] * invl);
            hv[2] = (f16)(o[n][2] * invl); hv[3] = (f16)(o[n][3] * invl);
            *reinterpret_cast<half4*>(
                &O[((size_t)(b * T_ + qg) * NH + h) * DH + n*16 + g*4]) = hv;
        }
    }
#undef STAGE_K
#undef STAGE_V
}

// ---------------- launch ----------------
extern "C" void kernel_launch(void* const* d_in, const int* in_sizes, int n_in,
                              void* d_out, int out_size, void* d_ws, size_t ws_size,
                              hipStream_t stream)
{
    const float* x  = (const float*)d_in[0];
    const float* wq = (const float*)d_in[1];
    const float* wk = (const float*)d_in[2];
    const float* wv = (const float*)d_in[3];
    const float* wo = (const float*)d_in[4];
    float* out = (float*)d_out;

    const size_t nx = (size_t)M_ * DM;   // 8388608
    const size_t nw = (size_t)DM * DM;   // 4194304
    const size_t need = (nx * 5 + nw * 4) * sizeof(f16);  // ~117 MB
    if (ws_size < need) return;

    char* ws = (char*)d_ws;
    f16* xh  = (f16*)ws;  ws += nx * 2;   // after qkv3: dead -> reused as V^T
    f16* wqh = (f16*)ws;  ws += nw * 2;   // wq,wk,wv contiguous -> fused B [6144,2048]
    f16* wkh = (f16*)ws;  ws += nw * 2;
    f16* wvh = (f16*)ws;  ws += nw * 2;
    f16* woh = (f16*)ws;  ws += nw * 2;
    f16* Qh  = (f16*)ws;  ws += nx * 2;   // Q,K,V contiguous -> fused dst
    f16* Kh  = (f16*)ws;  ws += nx * 2;
    f16* Vh  = (f16*)ws;  ws += nx * 2;
    f16* Oh  = (f16*)ws;  ws += nx * 2;

    f16* Vth = xh;   // V^T [B,H,DH,T] aliases xh (x consumed by qkv3 first)

    CvtArgs ca;
    ca.s[0] = x;  ca.d[0] = xh;
    ca.s[1] = wq; ca.d[1] = wqh;
    ca.s[2] = wk; ca.d[2] = wkh;
    ca.s[3] = wv; ca.d[3] = wvh;
    ca.s[4] = wo; ca.d[4] = woh;
    convert_all<<<24576, 256, 0, stream>>>(ca);

    qkv3<<<dim3(512), 512, 0, stream>>>(xh, wqh, Qh);

    vtrans<<<dim3(2, 32, 32), 256, 0, stream>>>(Vh, Vth);

    attn_fwd<<<dim3(512), 256, 0, stream>>>(Qh, Kh, Vth, Oh);

    wo2<<<dim3(512), 512, 0, stream>>>(Oh, woh, out);
}